// Round 3
// baseline (171.887 us; speedup 1.0000x reference)
//
#include <hip/hip_runtime.h>

// Multihead self-attention with 3-scale relative positional embeddings.
// B=4, S=1024, D=512, H=8, HD=64.  Outputs: out (4,1024,512) f32, attn (4,8,1024,1024) f32.
//
// Skew algebra (verified round 1):
//   Srel_q[i,j]  = q[i] . Er_q[1023 + j - i]
//   Srel_b[i,j]  = q[i] . Er_b[255 + (j>>2) - (i>>2)]
//   Srel_r[i,j]  = q[i] . Er_r[63  + (j>>4) - (i>>4)]
//
// Round-3 theory: kernel was latency-serialized (VGPR=40, no loads in flight).
// Fix = register prefetch of K/V fragments, 2-deep pipelines, coalesced attn
// store from LDS, vectorized RB/RR gathers.

typedef float f32x4 __attribute__((ext_vector_type(4)));
typedef short s16x8 __attribute__((ext_vector_type(8)));
typedef short s16x4 __attribute__((ext_vector_type(4)));
typedef __bf16 bf16x8 __attribute__((ext_vector_type(8)));

static __device__ __forceinline__ short f2bf(float f) {
    return __builtin_bit_cast(short, (__bf16)f);   // hw cvt
}
static __device__ __forceinline__ float bf2f(short s) {
    union { unsigned u; float f; } v;
    v.u = ((unsigned)(unsigned short)s) << 16;
    return v.f;
}
static __device__ __forceinline__ f32x4 MM(s16x8 a, s16x8 b, f32x4 c) {
    return __builtin_amdgcn_mfma_f32_16x16x32_bf16(
        __builtin_bit_cast(bf16x8, a), __builtin_bit_cast(bf16x8, b), c, 0, 0, 0);
}

// ---------------------------------------------------------------------------
// K0: one-shot f32 -> bf16 conversion of all reused operands.
// ---------------------------------------------------------------------------
struct CvtArgs {
    const float* src[9];
    short* dst[9];
    unsigned n[9];          // all divisible by 8
};

__global__ __launch_bounds__(256) void convert_kernel(CvtArgs a) {
    const int ai = blockIdx.y;
    const unsigned n = a.n[ai];
    const float* __restrict__ s = a.src[ai];
    short* __restrict__ d = a.dst[ai];
    const unsigned stride = gridDim.x * 256 * 8;
    for (unsigned base = (blockIdx.x * 256 + threadIdx.x) * 8; base < n; base += stride) {
        f32x4 v0 = *(const f32x4*)(s + base);
        f32x4 v1 = *(const f32x4*)(s + base + 4);
        s16x8 o;
        o[0] = f2bf(v0[0]); o[1] = f2bf(v0[1]); o[2] = f2bf(v0[2]); o[3] = f2bf(v0[3]);
        o[4] = f2bf(v1[0]); o[5] = f2bf(v1[1]); o[6] = f2bf(v1[2]); o[7] = f2bf(v1[3]);
        *(s16x8*)(d + base) = o;
    }
}

// ---------------------------------------------------------------------------
// K1: QKV projections (bf16 in, bf16 out).  One wave = 32x32 tile, 2x2 MFMA,
// 2-deep register pipeline over K.
// ---------------------------------------------------------------------------
__global__ __launch_bounds__(256, 4) void proj_kernel(
    const short* __restrict__ queryb, const short* __restrict__ keyb, const short* __restrict__ valueb,
    const short* __restrict__ Wqb, const float* __restrict__ bq,
    const short* __restrict__ Wkb, const float* __restrict__ bk,
    const short* __restrict__ Wvb, const float* __restrict__ bv,
    short* __restrict__ qb, short* __restrict__ kb, short* __restrict__ vT)
{
    const int tid = threadIdx.x;
    const int wid = tid >> 6, lane = tid & 63;
    const int l15 = lane & 15, grp = lane >> 4;
    const int gid = blockIdx.x * 4 + wid;     // 0..6143
    const int z = gid >> 11;                  // 0,1,2
    const int r = gid & 2047;

    const short *Am, *Bm;
    const float* bias;
    int a0, b0;
    if (z == 0)      { Am = queryb; Bm = Wqb;    bias = bq; a0 = (r >> 4) * 32; b0 = (r & 15) * 32; }
    else if (z == 1) { Am = keyb;   Bm = Wkb;    bias = bk; a0 = (r >> 4) * 32; b0 = (r & 15) * 32; }
    else             { Am = Wvb;    Bm = valueb; bias = bv; a0 = (r >> 7) * 32; b0 = (r & 127) * 32; }

    f32x4 acc[2][2];
    #pragma unroll
    for (int i = 0; i < 2; ++i)
        #pragma unroll
        for (int j = 0; j < 2; ++j)
            acc[i][j] = f32x4{0.f, 0.f, 0.f, 0.f};

    const short* arow0 = Am + (size_t)(a0 + l15) * 512 + grp * 8;
    const short* brow0 = Bm + (size_t)(b0 + l15) * 512 + grp * 8;

    s16x8 afA[2], bfA[2], afB[2], bfB[2];
    #pragma unroll
    for (int i = 0; i < 2; ++i) {
        afA[i] = *(const s16x8*)(arow0 + (size_t)i * 16 * 512);
        bfA[i] = *(const s16x8*)(brow0 + (size_t)i * 16 * 512);
    }
    for (int kk = 0; kk < 512; kk += 32) {
        const int kn = kk + 32;
        if (kn < 512) {
            #pragma unroll
            for (int i = 0; i < 2; ++i) {
                afB[i] = *(const s16x8*)(arow0 + (size_t)i * 16 * 512 + kn);
                bfB[i] = *(const s16x8*)(brow0 + (size_t)i * 16 * 512 + kn);
            }
        }
        #pragma unroll
        for (int i = 0; i < 2; ++i)
            #pragma unroll
            for (int j = 0; j < 2; ++j)
                acc[i][j] = MM(afA[i], bfA[j], acc[i][j]);
        #pragma unroll
        for (int i = 0; i < 2; ++i) { afA[i] = afB[i]; bfA[i] = bfB[i]; }
    }

    if (z < 2) {
        short* dst = (z == 0) ? qb : kb;
        #pragma unroll
        for (int j = 0; j < 2; ++j) {
            const int n = b0 + j * 16 + l15;      // feature col
            const float bval = bias[n];
            const int h = n >> 6, d = n & 63;
            #pragma unroll
            for (int i = 0; i < 2; ++i)
                #pragma unroll
                for (int g = 0; g < 4; ++g) {
                    const int m = a0 + i * 16 + grp * 4 + g;   // (b,s) row
                    const int bb = m >> 10, s = m & 1023;
                    dst[(size_t)((bb * 8 + h) * 1024 + s) * 64 + d] = f2bf(acc[i][j][g] + bval);
                }
        }
    } else {
        #pragma unroll
        for (int i = 0; i < 2; ++i)
            #pragma unroll
            for (int g = 0; g < 4; ++g) {
                const int n = a0 + i * 16 + grp * 4 + g;       // feature row
                const float bval = bias[n];
                const int h = n >> 6, d = n & 63;
                #pragma unroll
                for (int j = 0; j < 2; ++j) {
                    const int m = b0 + j * 16 + l15;           // (b,s) col
                    const int bb = m >> 10, s = m & 1023;
                    vT[(size_t)((bb * 8 + h) * 64 + d) * 1024 + s] = f2bf(acc[i][j][g] + bval);
                }
            }
    }
}

// ---------------------------------------------------------------------------
// K2: fused relative attention.  1 block = (b,h) x 16-row i-tile. 8 waves.
// LDS 44480B.  ILP-first: K frags preloaded pre-phase1, V frags prefetched
// during softmax, attn stored coalesced from PS.
//   RQ[16][1048] bf16 (33536B, reused as PS[16][1032])
//   RBT[260][16] bf16 (8320B, reused as PACC[8][16][16] f32)
//   RRT[64][16]  bf16 (2048B)
//   RSUM[8][16] f32, RINV[16] f32
// ---------------------------------------------------------------------------
__global__ __launch_bounds__(512, 4) void attn_kernel(
    const short* __restrict__ Eqb, const short* __restrict__ Ebb, const short* __restrict__ Errb,
    const short* __restrict__ qb, const short* __restrict__ kb, const short* __restrict__ vT,
    float* __restrict__ out, float* __restrict__ attn)
{
    __shared__ __align__(16) char smem[44480];
    short* RQ   = (short*)smem;                 // [16][1048]
    short* PS   = (short*)smem;                 // [16][1032] (reuse)
    short* RBT  = (short*)(smem + 33536);       // [260][16] transposed
    float* PACC = (float*)(smem + 33536);       // [8][16][16] (reuse of RBT)
    short* RRT  = (short*)(smem + 41856);       // [64][16] transposed
    float* RSUM = (float*)(smem + 43904);       // [8][16]
    float* RINV = (float*)(smem + 44416);       // [16]
    const int RQS = 1048, PSS = 1032;

    const int tid = threadIdx.x;
    const int wid = tid >> 6, lane = tid & 63;
    const int l15 = lane & 15, grp = lane >> 4;

    // XCD-aware bijective swizzle (nwg = 2048, %8 == 0)
    const int orig = blockIdx.x;
    const int bid = (orig & 7) * (2048 >> 3) + (orig >> 3);

    const int bh = bid >> 6;                  // b*8+h
    const int i0 = (bid & 63) << 4;
    const int h = bh & 7;

    const short* EqH = Eqb  + (size_t)h * 2047 * 64;
    const short* EbH = Ebb  + (size_t)h * 511 * 64;
    const short* ErH = Errb + (size_t)h * 127 * 64;
    const short* qbH = qb + (size_t)bh * 1024 * 64;
    const short* kbH = kb + (size_t)bh * 1024 * 64;
    const short* vTH = vT + (size_t)bh * 64 * 1024;

    // q A-fragments first (phase1 depends on them)
    s16x8 qfr[2];
    #pragma unroll
    for (int kh = 0; kh < 2; ++kh)
        qfr[kh] = *(const s16x8*)(qbH + (size_t)(i0 + l15) * 64 + kh * 32 + grp * 8);

    // Preload ALL K fragments for this wave's 8 tiles (64 VGPRs, in flight
    // across all of phase 1 -> latency fully hidden).
    s16x8 kf[8][2];
    #pragma unroll
    for (int t = 0; t < 8; ++t) {
        const short* kp = kbH + (size_t)(wid * 128 + t * 16 + l15) * 64 + grp * 8;
        kf[t][0] = *(const s16x8*)kp;
        kf[t][1] = *(const s16x8*)(kp + 32);
    }

    // ---- Phase 1: build relative tables via MFMA (q x Er^T) ----
    // RQ row-major; RBT/RRT transposed [col][row] for vector gathers.
    const int qbase = 1008 - i0;              // RQ col c -> Er_q row qbase+c
    {
        int cs = wid;
        int erow = qbase + cs * 16 + l15; if (erow > 2046) erow = 2046;
        const short* ep = EqH + (size_t)erow * 64 + grp * 8;
        s16x8 e0 = *(const s16x8*)ep;
        s16x8 e1 = *(const s16x8*)(ep + 32);
        while (cs < 65) {
            const int ns = cs + 8;
            s16x8 f0 = e0, f1 = e1;
            if (ns < 65) {
                int er2 = qbase + ns * 16 + l15; if (er2 > 2046) er2 = 2046;
                const short* ep2 = EqH + (size_t)er2 * 64 + grp * 8;
                f0 = *(const s16x8*)ep2;
                f1 = *(const s16x8*)(ep2 + 32);
            }
            f32x4 a = f32x4{0.f, 0.f, 0.f, 0.f};
            a = MM(qfr[0], e0, a);
            a = MM(qfr[1], e1, a);
            #pragma unroll
            for (int g = 0; g < 4; ++g)
                RQ[(grp * 4 + g) * RQS + cs * 16 + l15] = f2bf(a[g]);
            e0 = f0; e1 = f1; cs = ns;
        }
    }
    const int bbase = 252 - (i0 >> 2);        // RBT col c -> Er_b row bbase+c
    for (int cs = wid; cs < 17; cs += 8) {    // 260 cols (chunk 16 -> 272, clamped)
        int erow = bbase + cs * 16 + l15; if (erow > 510) erow = 510;
        const short* ep = EbH + (size_t)erow * 64 + grp * 8;
        s16x8 e0 = *(const s16x8*)ep;
        s16x8 e1 = *(const s16x8*)(ep + 32);
        f32x4 a = f32x4{0.f, 0.f, 0.f, 0.f};
        a = MM(qfr[0], e0, a);
        a = MM(qfr[1], e1, a);
        const int c = cs * 16 + l15;
        if (c < 260) {
            #pragma unroll
            for (int g = 0; g < 4; ++g)
                RBT[c * 16 + grp * 4 + g] = f2bf(a[g]);
        }
    }
    const int rbase = 63 - (i0 >> 4);         // RRT col c -> Er_r row rbase+c (always in-range)
    for (int cs = wid; cs < 4; cs += 8) {
        int erow = rbase + cs * 16 + l15;
        const short* ep = ErH + (size_t)erow * 64 + grp * 8;
        s16x8 e0 = *(const s16x8*)ep;
        s16x8 e1 = *(const s16x8*)(ep + 32);
        f32x4 a = f32x4{0.f, 0.f, 0.f, 0.f};
        a = MM(qfr[0], e0, a);
        a = MM(qfr[1], e1, a);
        #pragma unroll
        for (int g = 0; g < 4; ++g)
            RRT[(cs * 16 + l15) * 16 + grp * 4 + g] = f2bf(a[g]);
    }
    __syncthreads();

    // ---- loop 1: QK^T (K frags already in regs) + gathers + exp ----
    f32x4 p[8];
    #pragma unroll
    for (int t = 0; t < 8; ++t) {
        const int jb = wid * 128 + t * 16;
        const int j = jb + l15;
        f32x4 a = f32x4{0.f, 0.f, 0.f, 0.f};
        a = MM(qfr[0], kf[t][0], a);
        a = MM(qfr[1], kf[t][1], a);
        const int cb = (j >> 2) + 3 - grp;
        const int cr = jb >> 4;               // wave-uniform per t
        s16x4 rb4 = *(const s16x4*)&RBT[cb * 16 + grp * 4];
        s16x4 rr4 = *(const s16x4*)&RRT[cr * 16 + grp * 4];
        f32x4 pe;
        #pragma unroll
        for (int g = 0; g < 4; ++g) {
            const int ii = grp * 4 + g;
            const float gq = bf2f(RQ[ii * RQS + (j + 15 - ii)]);
            pe[g] = __expf((a[g] + gq + bf2f(rb4[g]) + bf2f(rr4[g])) * 0.125f);
        }
        p[t] = pe;
    }

    // ---- row sums: 16-lane butterfly + cross-wave LDS reduce ----
    f32x4 rs = p[0];
    #pragma unroll
    for (int t = 1; t < 8; ++t) rs += p[t];
    #pragma unroll
    for (int m = 1; m < 16; m <<= 1)
        #pragma unroll
        for (int g = 0; g < 4; ++g)
            rs[g] += __shfl_xor(rs[g], m, 64);
    if (l15 == 0) {
        #pragma unroll
        for (int g = 0; g < 4; ++g)
            RSUM[wid * 16 + grp * 4 + g] = rs[g];
    }
    __syncthreads();
    if (tid < 16) {
        float s = 0.f;
        #pragma unroll
        for (int w = 0; w < 8; ++w) s += RSUM[w * 16 + tid];
        RINV[tid] = 1.0f / s;
    }
    __syncthreads();

    // Prefetch ALL V fragments for this wave's PV tile (64 VGPRs); latency
    // hides under normalize + PS writes + barrier.
    const int c = wid >> 1, kh = wid & 1;
    const short* vrow = vTH + (size_t)(c * 16 + l15) * 1024 + kh * 512 + grp * 8;
    s16x8 vreg[16];
    #pragma unroll
    for (int kk = 0; kk < 16; ++kk)
        vreg[kk] = *(const s16x8*)(vrow + kk * 32);

    // ---- loop 2: normalize + stage bf16 P into LDS (RQ region dead now) ----
    float rinv[4];
    #pragma unroll
    for (int g = 0; g < 4; ++g) rinv[g] = RINV[grp * 4 + g];
    #pragma unroll
    for (int t = 0; t < 8; ++t) {
        const int jb = wid * 128 + t * 16;
        #pragma unroll
        for (int g = 0; g < 4; ++g) {
            const int ii = grp * 4 + g;
            PS[ii * PSS + jb + l15] = f2bf(p[t][g] * rinv[g]);
        }
    }
    __syncthreads();

    // ---- PV from LDS P + register V ----
    f32x4 acc = f32x4{0.f, 0.f, 0.f, 0.f};
    const short* prow = PS + (size_t)l15 * PSS + kh * 512 + grp * 8;
    #pragma unroll
    for (int kk = 0; kk < 16; ++kk) {
        s16x8 af = *(const s16x8*)(prow + kk * 32);
        acc = MM(af, vreg[kk], acc);
    }
    #pragma unroll
    for (int g = 0; g < 4; ++g)
        PACC[(wid * 16 + grp * 4 + g) * 16 + l15] = acc[g];

    // ---- coalesced attn store from PS (bf16 -> f32, 1KB/inst) ----
    {
        const float* rbase_attn = attn + (size_t)(bh * 1024 + i0) * 1024;
        #pragma unroll
        for (int rr = 0; rr < 2; ++rr) {
            const int row = wid * 2 + rr;
            float* arow = (float*)rbase_attn + (size_t)row * 1024;
            #pragma unroll
            for (int pass = 0; pass < 4; ++pass) {
                const int col = pass * 256 + lane * 4;
                s16x4 v4 = *(const s16x4*)&PS[row * PSS + col];
                f32x4 o;
                o[0] = bf2f(v4[0]); o[1] = bf2f(v4[1]);
                o[2] = bf2f(v4[2]); o[3] = bf2f(v4[3]);
                *(f32x4*)(arow + col) = o;
            }
        }
    }
    __syncthreads();

    // ---- split-K reduce + out store ----
    if (wid < 4) {
        const int b = bh >> 3;
        #pragma unroll
        for (int g = 0; g < 4; ++g) {
            const int row = grp * 4 + g;
            const float v = PACC[((2 * wid) * 16 + row) * 16 + l15]
                          + PACC[((2 * wid + 1) * 16 + row) * 16 + l15];
            out[(size_t)(b * 1024 + i0 + row) * 512 + h * 64 + wid * 16 + l15] = v;
        }
    }
}

// ---------------------------------------------------------------------------
extern "C" void kernel_launch(void* const* d_in, const int* in_sizes, int n_in,
                              void* d_out, int out_size, void* d_ws, size_t ws_size,
                              hipStream_t stream)
{
    const float* query = (const float*)d_in[0];
    const float* key   = (const float*)d_in[1];
    const float* value = (const float*)d_in[2];
    const float* Wq = (const float*)d_in[3];
    const float* bq = (const float*)d_in[4];
    const float* Wk = (const float*)d_in[5];
    const float* bk = (const float*)d_in[6];
    const float* Wv = (const float*)d_in[7];
    const float* bv = (const float*)d_in[8];
    const float* Eq = (const float*)d_in[9];
    const float* Eb = (const float*)d_in[10];
    const float* Er = (const float*)d_in[11];

    float* out  = (float*)d_out;
    float* attn = out + (size_t)4 * 1024 * 512;

    // workspace layout (shorts), ~29.5 MB total
    short* qb     = (short*)d_ws;
    short* kb     = qb     + 2097152;
    short* vT     = kb     + 2097152;
    short* queryb = vT     + 2097152;
    short* keyb   = queryb + 2097152;
    short* valueb = keyb   + 2097152;
    short* Wqb    = valueb + 2097152;
    short* Wkb    = Wqb    + 262144;
    short* Wvb    = Wkb    + 262144;
    short* Eqb    = Wvb    + 262144;
    short* Ebb    = Eqb    + 1048064;   // 8*2047*64
    short* Errb   = Ebb    + 261632;    // 8*511*64

    CvtArgs a;
    a.src[0] = query; a.dst[0] = queryb; a.n[0] = 2097152;
    a.src[1] = key;   a.dst[1] = keyb;   a.n[1] = 2097152;
    a.src[2] = value; a.dst[2] = valueb; a.n[2] = 2097152;
    a.src[3] = Wq;    a.dst[3] = Wqb;    a.n[3] = 262144;
    a.src[4] = Wk;    a.dst[4] = Wkb;    a.n[4] = 262144;
    a.src[5] = Wv;    a.dst[5] = Wvb;    a.n[5] = 262144;
    a.src[6] = Eq;    a.dst[6] = Eqb;    a.n[6] = 1048064;
    a.src[7] = Eb;    a.dst[7] = Ebb;    a.n[7] = 261632;
    a.src[8] = Er;    a.dst[8] = Errb;   a.n[8] = 65024;

    convert_kernel<<<dim3(1024, 9), 256, 0, stream>>>(a);
    proj_kernel<<<1536, 256, 0, stream>>>(queryb, keyb, valueb,
                                          Wqb, bq, Wkb, bk, Wvb, bv, qb, kb, vT);
    attn_kernel<<<2048, 512, 0, stream>>>(Eqb, Ebb, Errb, qb, kb, vT, out, attn);
}